// Round 5
// baseline (798.413 us; speedup 1.0000x reference)
//
#include <hip/hip_runtime.h>
#include <hip/hip_bf16.h>

#define HID 128
#define IN_DIM 16
#define LDST 136  // LDS row stride in bf16 elems: 272 B, 16B-aligned rows

typedef unsigned short u16;
typedef __attribute__((ext_vector_type(8))) short short8;
typedef __attribute__((ext_vector_type(4))) float f32x4;

__device__ __forceinline__ float bf2f(u16 u) { return __uint_as_float(((unsigned)u) << 16); }
__device__ __forceinline__ u16 f2b(float f) {  // RNE
    unsigned u = __float_as_uint(f);
    return (u16)((u + 0x7FFF + ((u >> 16) & 1)) >> 16);
}

// ---------------- CSR build ----------------

__global__ __launch_bounds__(256) void count_k(const int* __restrict__ dst, int* __restrict__ deg, int E) {
    int e = blockIdx.x * 256 + threadIdx.x;
    if (e < E) atomicAdd(&deg[dst[e]], 1);
}

__global__ __launch_bounds__(1024) void scan_k(const int* __restrict__ deg, int* __restrict__ row_ptr, int n) {
    __shared__ int sbuf[1024];
    int t = threadIdx.x;
    int chunk = (n + 1023) / 1024;
    int base = t * chunk;
    int end = base + chunk; if (end > n) end = n;
    int s = 0;
    for (int i = base; i < end; i++) s += deg[i];
    sbuf[t] = s;
    __syncthreads();
    for (int off = 1; off < 1024; off <<= 1) {
        int add = (t >= off) ? sbuf[t - off] : 0;
        __syncthreads();
        sbuf[t] += add;
        __syncthreads();
    }
    int run = (t > 0) ? sbuf[t - 1] : 0;
    for (int i = base; i < end; i++) { row_ptr[i] = run; run += deg[i]; }
    if (end == n) row_ptr[n] = run;
}

// cnt pre-seeded with row_ptr (d2d copy) -> atomic returns slot directly (short chain)
__global__ __launch_bounds__(256) void fill_k(const int* __restrict__ src, const int* __restrict__ dst,
                                              int* __restrict__ cnt, int* __restrict__ srcs, int E) {
    int e = blockIdx.x * 256 + threadIdx.x;
    if (e < E) {
        int d = dst[e];
        int p = atomicAdd(&cnt[d], 1);
        srcs[p] = src[e];
    }
}

// ---------------- weight prep: fp32 [K,128] -> bf16 [128][K] (n-major) ----------------

struct WJobs {
    const float* src[16];
    int dstoff[16];
    int ks[16];  // log2 K
};

__global__ __launch_bounds__(256) void wprep_k(WJobs j, u16* __restrict__ Wt) {
    int m = blockIdx.x;
    const float* s = j.src[m];
    u16* d = Wt + j.dstoff[m];
    int ks = j.ks[m];
    int K = 1 << ks;
    int tot = K * HID;
    for (int idx = threadIdx.x; idx < tot; idx += 256) {
        int nn = idx >> ks;
        int kk = idx & (K - 1);
        d[idx] = f2b(s[kk * HID + nn]);
    }
}

// ---------------- message aggregation: gather bf16 h rows, wave per dst ----------------

__global__ __launch_bounds__(256) void msg_k(const u16* __restrict__ hb, const int* __restrict__ row_ptr,
                                             const int* __restrict__ srcs, u16* __restrict__ msgb, int n) {
    int wave = threadIdx.x >> 6, lane = threadIdx.x & 63;
    int d = blockIdx.x * 4 + wave;
    if (d >= n) return;
    int e = row_ptr[d], e1 = row_ptr[d + 1];
    float a0 = 0.f, a1 = 0.f;
    for (; e + 3 < e1; e += 4) {
        int s0 = srcs[e], s1 = srcs[e + 1], s2 = srcs[e + 2], s3 = srcs[e + 3];
        unsigned v0 = *(const unsigned*)(hb + (size_t)s0 * HID + lane * 2);
        unsigned v1 = *(const unsigned*)(hb + (size_t)s1 * HID + lane * 2);
        unsigned v2 = *(const unsigned*)(hb + (size_t)s2 * HID + lane * 2);
        unsigned v3 = *(const unsigned*)(hb + (size_t)s3 * HID + lane * 2);
        a0 += __uint_as_float(v0 << 16) + __uint_as_float(v1 << 16) +
              __uint_as_float(v2 << 16) + __uint_as_float(v3 << 16);
        a1 += __uint_as_float(v0 & 0xffff0000u) + __uint_as_float(v1 & 0xffff0000u) +
              __uint_as_float(v2 & 0xffff0000u) + __uint_as_float(v3 & 0xffff0000u);
    }
    for (; e < e1; e++) {
        unsigned v = *(const unsigned*)(hb + (size_t)srcs[e] * HID + lane * 2);
        a0 += __uint_as_float(v << 16);
        a1 += __uint_as_float(v & 0xffff0000u);
    }
    unsigned out = (unsigned)f2b(a0) | ((unsigned)f2b(a1) << 16);
    *(unsigned*)(msgb + (size_t)d * HID + lane * 2) = out;
}

// ---------------- MFMA GEMM: C[64 x 128] tile, 4 waves (2x2), 16x16x32 bf16 ----------------

__device__ __forceinline__ void stageA128(const u16* __restrict__ A, int row0, int tid, u16* sA) {
#pragma unroll
    for (int q = 0; q < 4; q++) {
        int c = tid + q * 256;
        int row = c >> 4, j8 = c & 15;
        uint4 v = *(const uint4*)(A + (size_t)(row0 + row) * HID + j8 * 8);
        *(uint4*)(sA + row * LDST + j8 * 8) = v;
    }
}

__device__ __forceinline__ void stageW128(const u16* __restrict__ Wt, int tid, u16* sB) {
#pragma unroll
    for (int q = 0; q < 8; q++) {
        int c = tid + q * 256;
        int row = c >> 4, j8 = c & 15;
        uint4 v = *(const uint4*)(Wt + row * HID + j8 * 8);
        *(uint4*)(sB + row * LDST + j8 * 8) = v;
    }
}

__device__ __forceinline__ void stageFeat(const float* __restrict__ feat, int row0, int n, int tid, u16* sA) {
    int row = tid >> 2, coff = tid & 3;
    ushort4 o = make_ushort4(0, 0, 0, 0);
    if (row0 + row < n) {
        float4 v = *(const float4*)(feat + (size_t)(row0 + row) * IN_DIM + coff * 4);
        o = make_ushort4(f2b(v.x), f2b(v.y), f2b(v.z), f2b(v.w));
    }
    *(ushort4*)(sA + row * LDST + coff * 4) = o;
    *(ushort4*)(sA + row * LDST + 16 + coff * 4) = make_ushort4(0, 0, 0, 0);  // zero-pad K 16->32
}

__device__ __forceinline__ void stageW16(const u16* __restrict__ Wt, int tid, u16* sB) {
    int row = tid >> 1, h8 = tid & 1;
    uint4 v = *(const uint4*)(Wt + row * IN_DIM + h8 * 8);
    *(uint4*)(sB + row * LDST + h8 * 8) = v;
    *(uint4*)(sB + row * LDST + 16 + h8 * 8) = make_uint4(0, 0, 0, 0);
}

template <int KSTEPS>
__device__ __forceinline__ void mac(const u16* sA, const u16* sB, int wrow, int wcol,
                                    int ln15, int quad, f32x4 acc[2][4]) {
#pragma unroll
    for (int kk = 0; kk < KSTEPS; kk++) {
        short8 a[2], b[4];
#pragma unroll
        for (int mi = 0; mi < 2; mi++)
            a[mi] = *(const short8*)(sA + (wrow + mi * 16 + ln15) * LDST + kk * 32 + quad * 8);
#pragma unroll
        for (int ni = 0; ni < 4; ni++)
            b[ni] = *(const short8*)(sB + (wcol + ni * 16 + ln15) * LDST + kk * 32 + quad * 8);
#pragma unroll
        for (int mi = 0; mi < 2; mi++)
#pragma unroll
            for (int ni = 0; ni < 4; ni++)
                acc[mi][ni] = __builtin_amdgcn_mfma_f32_16x16x32_bf16(a[mi], b[ni], acc[mi][ni], 0, 0, 0);
    }
}

// MODE 0: A = feat fp32 [n,16]; MODE 1: A = bf16 [n,128]; MODE 2: dual-K + inline grW bias
// COLSUM: epilogue accumulates column sums of C into gsumOut (device atomics)
template <int MODE, bool RELU, bool OUTF, bool OUTB, bool COLSUM>
__global__ __launch_bounds__(256) void mgemm_k(const void* __restrict__ Araw, const u16* __restrict__ Wt,
                                               const u16* __restrict__ A2, const u16* __restrict__ Wt2,
                                               const float* __restrict__ bias, const float* __restrict__ gsumIn,
                                               const float* __restrict__ Wg, float* __restrict__ Cf,
                                               u16* __restrict__ Cb, float* __restrict__ gsumOut, int n) {
    __shared__ u16 sA[64 * LDST];
    __shared__ u16 sB[128 * LDST];
    __shared__ float s_gr[HID];
    __shared__ float s_grW[HID];
    __shared__ float s_red[2];
    int tid = threadIdx.x;
    int lane = tid & 63, wave = tid >> 6;
    int ln15 = lane & 15, quad = lane >> 4;
    int wrow = (wave >> 1) * 32, wcol = (wave & 1) * 64;
    int row0 = blockIdx.x * 64;

    f32x4 acc[2][4];

    if (MODE == 0) {
        stageFeat((const float*)Araw, row0, n, tid, sA);
        stageW16(Wt, tid, sB);
#pragma unroll
        for (int ni = 0; ni < 4; ni++) {
            float bv = bias[wcol + ni * 16 + ln15];
#pragma unroll
            for (int mi = 0; mi < 2; mi++) acc[mi][ni] = (f32x4){bv, bv, bv, bv};
        }
        __syncthreads();
        mac<1>(sA, sB, wrow, wcol, ln15, quad, acc);
    } else if (MODE == 1) {
        stageA128((const u16*)Araw, row0, tid, sA);
        stageW128(Wt, tid, sB);
#pragma unroll
        for (int ni = 0; ni < 4; ni++) {
            float bv = bias[wcol + ni * 16 + ln15];
#pragma unroll
            for (int mi = 0; mi < 2; mi++) acc[mi][ni] = (f32x4){bv, bv, bv, bv};
        }
        __syncthreads();
        mac<4>(sA, sB, wrow, wcol, ln15, quad, acc);
    } else {
        // MODE 2: stage first (loads in flight), then compute grW = b0 + rownorm(gsum) @ Wg inline
        stageA128((const u16*)Araw, row0, tid, sA);
        stageW128(Wt, tid, sB);
        if (tid < HID) {
            float g = gsumIn[tid];
            float s = g * g;
#pragma unroll
            for (int off = 1; off < 64; off <<= 1) s += __shfl_xor(s, off);
            if ((tid & 63) == 0) s_red[tid >> 6] = s;
        }
        __syncthreads();
        if (tid < HID) {
            float inv = 1.f / (sqrtf(s_red[0] + s_red[1]) + 1e-8f);
            s_gr[tid] = gsumIn[tid] * inv;
        }
        __syncthreads();
        if (tid < HID) {
            float a = bias[tid];
#pragma unroll 4
            for (int k = 0; k < HID; k++) a += s_gr[k] * Wg[k * HID + tid];
            s_grW[tid] = a;
        }
        __syncthreads();  // covers staging + s_grW
#pragma unroll
        for (int ni = 0; ni < 4; ni++) {
            float bv = s_grW[wcol + ni * 16 + ln15];
#pragma unroll
            for (int mi = 0; mi < 2; mi++) acc[mi][ni] = (f32x4){bv, bv, bv, bv};
        }
        mac<4>(sA, sB, wrow, wcol, ln15, quad, acc);
        __syncthreads();
        stageA128(A2, row0, tid, sA);
        stageW128(Wt2, tid, sB);
        __syncthreads();
        mac<4>(sA, sB, wrow, wcol, ln15, quad, acc);
    }

    // epilogue: C/D layout col=lane&15, row=quad*4+reg  [m89-verified]
    float csum[4] = {0.f, 0.f, 0.f, 0.f};
#pragma unroll
    for (int mi = 0; mi < 2; mi++)
#pragma unroll
        for (int r = 0; r < 4; r++) {
            int row = row0 + wrow + mi * 16 + quad * 4 + r;
            if (row < n) {
#pragma unroll
                for (int ni = 0; ni < 4; ni++) {
                    float v = acc[mi][ni][r];
                    if (RELU) v = fmaxf(v, 0.f);
                    int col = wcol + ni * 16 + ln15;
                    if (OUTF) Cf[(size_t)row * HID + col] = v;
                    if (OUTB) Cb[(size_t)row * HID + col] = f2b(v);
                    if (COLSUM) csum[ni] += v;
                }
            }
        }

    if (COLSUM) {
        __syncthreads();                    // done with sA -> reuse as reduction scratch
        float* s_cs = (float*)sA;
        if (tid < HID) s_cs[tid] = 0.f;
        __syncthreads();
#pragma unroll
        for (int ni = 0; ni < 4; ni++) {
            float p = csum[ni];
            p += __shfl_xor(p, 16);
            p += __shfl_xor(p, 32);         // sum over quads (rows of this wave)
            if (quad == 0) atomicAdd(&s_cs[wcol + ni * 16 + ln15], p);
        }
        __syncthreads();
        if (tid < HID) atomicAdd(&gsumOut[tid], s_cs[tid]);
    }
}

// ---------------- row-norm + has_in mask, fused column-sum for next iter ----------------

__global__ __launch_bounds__(256) void norm_where_k(const float* __restrict__ t3, const int* __restrict__ deg,
                                                    float* __restrict__ h, u16* __restrict__ hb,
                                                    float* __restrict__ gsumN, int n) {
    __shared__ float s_cs[HID];
    int tid = threadIdx.x;
    int wave = tid >> 6, lane = tid & 63;
    float c0 = 0.f, c1 = 0.f;
    for (int r = blockIdx.x * 4 + wave; r < n; r += gridDim.x * 4) {
        float2 v = *(const float2*)(t3 + (size_t)r * HID + lane * 2);
        float s = v.x * v.x + v.y * v.y;
#pragma unroll
        for (int off = 1; off < 64; off <<= 1) s += __shfl_xor(s, off);
        float2 o;
        if (deg[r] > 0) {
            float inv = 1.f / (sqrtf(s) + 1e-8f);
            o.x = v.x * inv; o.y = v.y * inv;
            *(float2*)(h + (size_t)r * HID + lane * 2) = o;
            unsigned pb = (unsigned)f2b(o.x) | ((unsigned)f2b(o.y) << 16);
            *(unsigned*)(hb + (size_t)r * HID + lane * 2) = pb;
        } else {
            o = *(const float2*)(h + (size_t)r * HID + lane * 2);
        }
        c0 += o.x; c1 += o.y;
    }
    if (gsumN) {
        if (tid < HID) s_cs[tid] = 0.f;
        __syncthreads();
        atomicAdd(&s_cs[lane * 2], c0);
        atomicAdd(&s_cs[lane * 2 + 1], c1);
        __syncthreads();
        if (tid < HID) atomicAdd(&gsumN[tid], s_cs[tid]);
    }
}

// ---------------- launch ----------------

static inline char* align_up(char* p, size_t a) {
    return (char*)(((uintptr_t)p + a - 1) & ~(uintptr_t)(a - 1));
}

extern "C" void kernel_launch(void* const* d_in, const int* in_sizes, int n_in,
                              void* d_out, int out_size, void* d_ws, size_t ws_size,
                              hipStream_t stream) {
    const float* feat = (const float*)d_in[0];
    const int* src = (const int*)d_in[1];
    const int* dst = (const int*)d_in[2];
    const float* iW0 = (const float*)d_in[3];
    const float* ib0 = (const float*)d_in[4];
    const float* iW1 = (const float*)d_in[5];
    const float* ib1 = (const float*)d_in[6];
    const float* iW2 = (const float*)d_in[7];
    const float* ib2 = (const float*)d_in[8];
    const float* nW0 = (const float*)d_in[9];
    const float* nb0 = (const float*)d_in[10];
    const float* nW1 = (const float*)d_in[11];
    const float* nb1 = (const float*)d_in[12];
    const float* nW2 = (const float*)d_in[13];
    const float* nb2 = (const float*)d_in[14];

    int N = in_sizes[0] / IN_DIM;
    int E = in_sizes[1];
    int n_iter = in_sizes[10] / HID;
    float* h = (float*)d_out;

    char* w = (char*)d_ws;
    size_t big4 = (size_t)(N + 64) * HID * sizeof(float);
    size_t big2 = (size_t)(N + 64) * HID * sizeof(u16);
    float* t3 = (float*)w; w += big4;
    u16* hb   = (u16*)w; w += big2;
    u16* msgb = (u16*)w; w += big2;
    u16* t1b  = (u16*)w; w += big2;
    u16* t2b  = (u16*)w; w += big2;
    float* gsums = (float*)w; w += (size_t)(n_iter + 1) * HID * sizeof(float);
    u16* Wt = (u16*)w; w += (size_t)(2048 + 2 * 16384 + n_iter * 4 * 16384) * sizeof(u16);
    w = align_up(w, 16);
    int* deg = (int*)w; w += (size_t)N * 4;  w = align_up(w, 16);
    int* row_ptr = (int*)w; w += (size_t)(N + 1) * 4;  w = align_up(w, 16);
    int* cnt = (int*)w; w += (size_t)N * 4;  w = align_up(w, 16);
    int* srcs = (int*)w; w += (size_t)E * 4;
    (void)ws_size; (void)n_in; (void)out_size;

    // Wt layout offsets (bf16 elems)
    const int OFF_IW0 = 0;
    const int OFF_IW1 = 2048;
    const int OFF_IW2 = 2048 + 16384;
    const int OFF_IT = 2048 + 2 * 16384;  // per iter: W0a, W0b, W1, W2 (4 x 16384)

    WJobs jobs;
    int nj = 0;
    jobs.src[nj] = iW0; jobs.dstoff[nj] = OFF_IW0; jobs.ks[nj] = 4; nj++;
    jobs.src[nj] = iW1; jobs.dstoff[nj] = OFF_IW1; jobs.ks[nj] = 7; nj++;
    jobs.src[nj] = iW2; jobs.dstoff[nj] = OFF_IW2; jobs.ks[nj] = 7; nj++;
    for (int i = 0; i < n_iter && nj + 4 <= 16; i++) {
        int base = OFF_IT + i * 4 * 16384;
        jobs.src[nj] = nW0 + (size_t)i * 3 * HID * HID;               jobs.dstoff[nj] = base;             jobs.ks[nj] = 7; nj++;
        jobs.src[nj] = nW0 + (size_t)i * 3 * HID * HID + HID * HID;   jobs.dstoff[nj] = base + 16384;     jobs.ks[nj] = 7; nj++;
        jobs.src[nj] = nW1 + (size_t)i * HID * HID;                   jobs.dstoff[nj] = base + 2 * 16384; jobs.ks[nj] = 7; nj++;
        jobs.src[nj] = nW2 + (size_t)i * HID * HID;                   jobs.dstoff[nj] = base + 3 * 16384; jobs.ks[nj] = 7; nj++;
    }

    hipMemsetAsync(deg, 0, (size_t)N * 4, stream);
    hipMemsetAsync(gsums, 0, (size_t)(n_iter + 1) * HID * sizeof(float), stream);

    wprep_k<<<nj, 256, 0, stream>>>(jobs, Wt);

    int eg = (E + 255) / 256;
    count_k<<<eg, 256, 0, stream>>>(dst, deg, E);
    scan_k<<<1, 1024, 0, stream>>>(deg, row_ptr, N);
    hipMemcpyAsync(cnt, row_ptr, (size_t)N * 4, hipMemcpyDeviceToDevice, stream);
    fill_k<<<eg, 256, 0, stream>>>(src, dst, cnt, srcs, E);

    int gb = (N + 63) / 64;
    int rb = (N + 3) / 4;
    // init MLP: feat -> t1b -> t2b -> h (+hb), colsum -> gsums[0]
    mgemm_k<0, true,  false, true,  false><<<gb, 256, 0, stream>>>(feat, Wt + OFF_IW0, nullptr, nullptr, ib0,
                                                                   nullptr, nullptr, nullptr, t1b, nullptr, N);
    mgemm_k<1, true,  false, true,  false><<<gb, 256, 0, stream>>>(t1b,  Wt + OFF_IW1, nullptr, nullptr, ib1,
                                                                   nullptr, nullptr, nullptr, t2b, nullptr, N);
    mgemm_k<1, false, true,  true,  true ><<<gb, 256, 0, stream>>>(t2b,  Wt + OFF_IW2, nullptr, nullptr, ib2,
                                                                   nullptr, nullptr, h, hb, gsums, N);

    for (int i = 0; i < n_iter; i++) {
        const u16* Wit = Wt + OFF_IT + (size_t)i * 4 * 16384;
        const float* Wg = nW0 + (size_t)i * 3 * HID * HID + 2 * HID * HID;
        msg_k<<<rb, 256, 0, stream>>>(hb, row_ptr, srcs, msgb, N);
        mgemm_k<2, true,  false, true,  false><<<gb, 256, 0, stream>>>(msgb, Wit, hb, Wit + 16384,
                                                                       nb0 + (size_t)i * HID, gsums + (size_t)i * HID,
                                                                       Wg, nullptr, t1b, nullptr, N);
        mgemm_k<1, true,  false, true,  false><<<gb, 256, 0, stream>>>(t1b, Wit + 2 * 16384, nullptr, nullptr,
                                                                       nb1 + (size_t)i * HID, nullptr, nullptr,
                                                                       nullptr, t2b, nullptr, N);
        mgemm_k<1, false, true,  false, false><<<gb, 256, 0, stream>>>(t2b, Wit + 3 * 16384, nullptr, nullptr,
                                                                       nb2 + (size_t)i * HID, nullptr, nullptr,
                                                                       t3, nullptr, nullptr, N);
        float* gsumN = (i + 1 < n_iter) ? (gsums + (size_t)(i + 1) * HID) : nullptr;
        norm_where_k<<<512, 256, 0, stream>>>(t3, deg, h, hb, gsumN, N);
    }
}

// Round 6
// 757.081 us; speedup vs baseline: 1.0546x; 1.0546x over previous
//
#include <hip/hip_runtime.h>
#include <hip/hip_bf16.h>

#define HID 128
#define IN_DIM 16
#define LDST 136   // LDS row stride in bf16 elems (272 B)
#define NBSH 7     // coarse bucket = dst >> 7  (128 dsts/bucket)
#define BPAD 16    // bucket counter padding (ints) -> one 64B line per counter

typedef unsigned short u16;
typedef __attribute__((ext_vector_type(8))) short short8;
typedef __attribute__((ext_vector_type(4))) float f32x4;

__device__ __forceinline__ u16 f2b(float f) {  // RNE
    unsigned u = __float_as_uint(f);
    return (u16)((u + 0x7FFF + ((u >> 16) & 1)) >> 16);
}

// ---------------- CSR build ----------------

__global__ __launch_bounds__(256) void count_k(const int* __restrict__ dst, int* __restrict__ deg, int E) {
    int e = blockIdx.x * 256 + threadIdx.x;
    if (e < E) atomicAdd(&deg[dst[e]], 1);
}

// prefix-scan deg -> row_ptr; also seed cnt (=row_ptr) and padded bucket counters
__global__ __launch_bounds__(1024) void scan_k(const int* __restrict__ deg, int* __restrict__ row_ptr,
                                               int* __restrict__ cnt, int* __restrict__ bcnt,
                                               int n, int nb) {
    __shared__ int sbuf[1024];
    int t = threadIdx.x;
    int chunk = (n + 1023) / 1024;
    int base = t * chunk;
    int end = base + chunk; if (end > n) end = n;
    int s = 0;
    for (int i = base; i < end; i++) s += deg[i];
    sbuf[t] = s;
    __syncthreads();
    for (int off = 1; off < 1024; off <<= 1) {
        int add = (t >= off) ? sbuf[t - off] : 0;
        __syncthreads();
        sbuf[t] += add;
        __syncthreads();
    }
    int run = (t > 0) ? sbuf[t - 1] : 0;
    for (int i = base; i < end; i++) { row_ptr[i] = run; run += deg[i]; }
    if (end == n) row_ptr[n] = run;
    __syncthreads();
    for (int i = t; i < n; i += 1024) cnt[i] = row_ptr[i];
    for (int b = t; b < nb; b += 1024) bcnt[b * BPAD] = row_ptr[b << NBSH];
}

// coarse bin: scatter (src,dst) into bucket-contiguous ebuf (dense write set -> L2 merges)
__global__ __launch_bounds__(256) void bin_k(const int* __restrict__ src, const int* __restrict__ dst,
                                             int* __restrict__ bcnt, int2* __restrict__ ebuf, int E) {
    int e = blockIdx.x * 256 + threadIdx.x;
    if (e < E) {
        int d = dst[e];
        int q = atomicAdd(&bcnt[(d >> NBSH) * BPAD], 1);
        ebuf[q] = make_int2(src[e], d);
    }
}

// block per bucket: final scatter within a small row_ptr window (block-local writes)
__global__ __launch_bounds__(256) void fill2_k(const int2* __restrict__ ebuf, const int* __restrict__ row_ptr,
                                               int* __restrict__ cnt, int* __restrict__ srcs, int n) {
    int b = blockIdx.x;
    int d0 = b << NBSH;
    int dend = d0 + (1 << NBSH); if (dend > n) dend = n;
    int e0 = row_ptr[d0], e1 = row_ptr[dend];
    for (int i = e0 + threadIdx.x; i < e1; i += 256) {
        int2 p = ebuf[i];
        int pos = atomicAdd(&cnt[p.y], 1);
        srcs[pos] = p.x;
    }
}

// ---------------- weight prep: fp32 [K,128] -> bf16 [128][K] (n-major) ----------------

struct WJobs {
    const float* src[16];
    int dstoff[16];
    int ks[16];  // log2 K
};

__global__ __launch_bounds__(256) void wprep_k(WJobs j, u16* __restrict__ Wt) {
    int m = blockIdx.x;
    const float* s = j.src[m];
    u16* d = Wt + j.dstoff[m];
    int ks = j.ks[m];
    int K = 1 << ks;
    int tot = K * HID;
    for (int idx = threadIdx.x; idx < tot; idx += 256) {
        int nn = idx >> ks;
        int kk = idx & (K - 1);
        d[idx] = f2b(s[kk * HID + nn]);
    }
}

// ---------------- message aggregation: gather bf16 h rows, wave per dst ----------------

__global__ __launch_bounds__(256) void msg_k(const u16* __restrict__ hb, const int* __restrict__ row_ptr,
                                             const int* __restrict__ srcs, u16* __restrict__ msgb, int n) {
    int wave = threadIdx.x >> 6, lane = threadIdx.x & 63;
    int d = blockIdx.x * 4 + wave;
    if (d >= n) return;
    int e = row_ptr[d], e1 = row_ptr[d + 1];
    float a0 = 0.f, a1 = 0.f;
    for (; e + 3 < e1; e += 4) {
        int s0 = srcs[e], s1 = srcs[e + 1], s2 = srcs[e + 2], s3 = srcs[e + 3];
        unsigned v0 = *(const unsigned*)(hb + (size_t)s0 * HID + lane * 2);
        unsigned v1 = *(const unsigned*)(hb + (size_t)s1 * HID + lane * 2);
        unsigned v2 = *(const unsigned*)(hb + (size_t)s2 * HID + lane * 2);
        unsigned v3 = *(const unsigned*)(hb + (size_t)s3 * HID + lane * 2);
        a0 += __uint_as_float(v0 << 16) + __uint_as_float(v1 << 16) +
              __uint_as_float(v2 << 16) + __uint_as_float(v3 << 16);
        a1 += __uint_as_float(v0 & 0xffff0000u) + __uint_as_float(v1 & 0xffff0000u) +
              __uint_as_float(v2 & 0xffff0000u) + __uint_as_float(v3 & 0xffff0000u);
    }
    for (; e < e1; e++) {
        unsigned v = *(const unsigned*)(hb + (size_t)srcs[e] * HID + lane * 2);
        a0 += __uint_as_float(v << 16);
        a1 += __uint_as_float(v & 0xffff0000u);
    }
    unsigned out = (unsigned)f2b(a0) | ((unsigned)f2b(a1) << 16);
    *(unsigned*)(msgb + (size_t)d * HID + lane * 2) = out;
}

// ---------------- MFMA building blocks: 64x128 C-tile, 4 waves (2x2), 16x16x32 bf16 ----------------

__device__ __forceinline__ void stageA128(const u16* __restrict__ A, int row0, int tid, u16* sA) {
#pragma unroll
    for (int q = 0; q < 4; q++) {
        int c = tid + q * 256;
        int row = c >> 4, j8 = c & 15;
        uint4 v = *(const uint4*)(A + (size_t)(row0 + row) * HID + j8 * 8);
        *(uint4*)(sA + row * LDST + j8 * 8) = v;
    }
}

__device__ __forceinline__ void stageW128(const u16* __restrict__ Wt, int tid, u16* sB) {
#pragma unroll
    for (int q = 0; q < 8; q++) {
        int c = tid + q * 256;
        int row = c >> 4, j8 = c & 15;
        uint4 v = *(const uint4*)(Wt + row * HID + j8 * 8);
        *(uint4*)(sB + row * LDST + j8 * 8) = v;
    }
}

__device__ __forceinline__ void stageFeat(const float* __restrict__ feat, int row0, int n, int tid, u16* sA) {
    int row = tid >> 2, coff = tid & 3;
    ushort4 o = make_ushort4(0, 0, 0, 0);
    if (row0 + row < n) {
        float4 v = *(const float4*)(feat + (size_t)(row0 + row) * IN_DIM + coff * 4);
        o = make_ushort4(f2b(v.x), f2b(v.y), f2b(v.z), f2b(v.w));
    }
    *(ushort4*)(sA + row * LDST + coff * 4) = o;
    *(ushort4*)(sA + row * LDST + 16 + coff * 4) = make_ushort4(0, 0, 0, 0);  // zero-pad K 16->32
}

__device__ __forceinline__ void stageW16(const u16* __restrict__ Wt, int tid, u16* sB) {
    int row = tid >> 1, h8 = tid & 1;
    uint4 v = *(const uint4*)(Wt + row * IN_DIM + h8 * 8);
    *(uint4*)(sB + row * LDST + h8 * 8) = v;
    *(uint4*)(sB + row * LDST + 16 + h8 * 8) = make_uint4(0, 0, 0, 0);
}

template <int KSTEPS>
__device__ __forceinline__ void mac(const u16* sA, const u16* sB, int wrow, int wcol,
                                    int ln15, int quad, f32x4 acc[2][4]) {
#pragma unroll
    for (int kk = 0; kk < KSTEPS; kk++) {
        short8 a[2], b[4];
#pragma unroll
        for (int mi = 0; mi < 2; mi++)
            a[mi] = *(const short8*)(sA + (wrow + mi * 16 + ln15) * LDST + kk * 32 + quad * 8);
#pragma unroll
        for (int ni = 0; ni < 4; ni++)
            b[ni] = *(const short8*)(sB + (wcol + ni * 16 + ln15) * LDST + kk * 32 + quad * 8);
#pragma unroll
        for (int mi = 0; mi < 2; mi++)
#pragma unroll
            for (int ni = 0; ni < 4; ni++)
                acc[mi][ni] = __builtin_amdgcn_mfma_f32_16x16x32_bf16(a[mi], b[ni], acc[mi][ni], 0, 0, 0);
    }
}

__device__ __forceinline__ void set_bias(f32x4 acc[2][4], const float* __restrict__ bias, int wcol, int ln15) {
#pragma unroll
    for (int ni = 0; ni < 4; ni++) {
        float bv = bias[wcol + ni * 16 + ln15];
#pragma unroll
        for (int mi = 0; mi < 2; mi++) acc[mi][ni] = (f32x4){bv, bv, bv, bv};
    }
}

// relu(acc) -> sA in [row][col] layout (== next layer's A-operand layout)
__device__ __forceinline__ void acc_to_sA(const f32x4 acc[2][4], u16* sA, int wrow, int wcol,
                                          int ln15, int quad) {
#pragma unroll
    for (int mi = 0; mi < 2; mi++)
#pragma unroll
        for (int r = 0; r < 4; r++) {
            int row = wrow + mi * 16 + quad * 4 + r;
#pragma unroll
            for (int ni = 0; ni < 4; ni++)
                sA[row * LDST + wcol + ni * 16 + ln15] = f2b(fmaxf(acc[mi][ni][r], 0.f));
        }
}

// ---------------- fused init MLP: feat -> relu -> relu -> h (+hb) + colsum ----------------

__global__ __launch_bounds__(256, 3) void init_fused_k(const float* __restrict__ feat,
                                                       const u16* __restrict__ W0t, const u16* __restrict__ W1t,
                                                       const u16* __restrict__ W2t,
                                                       const float* __restrict__ b0, const float* __restrict__ b1,
                                                       const float* __restrict__ b2,
                                                       float* __restrict__ h, u16* __restrict__ hb,
                                                       float* __restrict__ gsum0, int n) {
    __shared__ u16 sA[64 * LDST];
    __shared__ u16 sB[128 * LDST];
    int tid = threadIdx.x;
    int lane = tid & 63, wave = tid >> 6;
    int ln15 = lane & 15, quad = lane >> 4;
    int wrow = (wave >> 1) * 32, wcol = (wave & 1) * 64;
    int row0 = blockIdx.x * 64;
    f32x4 acc[2][4];

    stageFeat(feat, row0, n, tid, sA);
    stageW16(W0t, tid, sB);
    set_bias(acc, b0, wcol, ln15);
    __syncthreads();
    mac<1>(sA, sB, wrow, wcol, ln15, quad, acc);
    __syncthreads();
    acc_to_sA(acc, sA, wrow, wcol, ln15, quad);
    stageW128(W1t, tid, sB);
    set_bias(acc, b1, wcol, ln15);
    __syncthreads();
    mac<4>(sA, sB, wrow, wcol, ln15, quad, acc);
    __syncthreads();
    acc_to_sA(acc, sA, wrow, wcol, ln15, quad);
    stageW128(W2t, tid, sB);
    set_bias(acc, b2, wcol, ln15);
    __syncthreads();
    mac<4>(sA, sB, wrow, wcol, ln15, quad, acc);

    // epilogue: h (f32) + hb (bf16) + column-sum -> gsum0
    float csum[4] = {0.f, 0.f, 0.f, 0.f};
#pragma unroll
    for (int mi = 0; mi < 2; mi++)
#pragma unroll
        for (int r = 0; r < 4; r++) {
            int row = row0 + wrow + mi * 16 + quad * 4 + r;
            if (row < n) {
#pragma unroll
                for (int ni = 0; ni < 4; ni++) {
                    float v = acc[mi][ni][r];
                    int col = wcol + ni * 16 + ln15;
                    h[(size_t)row * HID + col] = v;
                    hb[(size_t)row * HID + col] = f2b(v);
                    csum[ni] += v;
                }
            }
        }
    __syncthreads();
    float* s_cs = (float*)sA;
    if (tid < HID) s_cs[tid] = 0.f;
    __syncthreads();
#pragma unroll
    for (int ni = 0; ni < 4; ni++) {
        float p = csum[ni];
        p += __shfl_xor(p, 16);
        p += __shfl_xor(p, 32);
        if (quad == 0) atomicAdd(&s_cs[wcol + ni * 16 + ln15], p);
    }
    __syncthreads();
    if (tid < HID) atomicAdd(&gsum0[tid], s_cs[tid]);
}

// ---------------- fused node update: (msg@W0a + h@W0b + grW) -> relu -> relu -> rownorm+mask (+colsum) ----------------

template <bool COLSUM>
__global__ __launch_bounds__(256, 3) void node_fused_k(const u16* __restrict__ msgb, const u16* __restrict__ hbin,
                                                       const u16* __restrict__ W0a, const u16* __restrict__ W0b,
                                                       const u16* __restrict__ W1t, const u16* __restrict__ W2t,
                                                       const float* __restrict__ b0, const float* __restrict__ Wg,
                                                       const float* __restrict__ gsumIn,
                                                       const float* __restrict__ b1, const float* __restrict__ b2,
                                                       const int* __restrict__ deg,
                                                       float* __restrict__ h, u16* __restrict__ hb,
                                                       float* __restrict__ gsumOut, int n) {
    __shared__ u16 sA[64 * LDST];
    __shared__ u16 sB[128 * LDST];
    __shared__ float s_gr[HID];
    __shared__ float s_grW[HID];
    __shared__ float s_red[2];
    int tid = threadIdx.x;
    int lane = tid & 63, wave = tid >> 6;
    int ln15 = lane & 15, quad = lane >> 4;
    int wrow = (wave >> 1) * 32, wcol = (wave & 1) * 64;
    int row0 = blockIdx.x * 64;
    f32x4 acc[2][4];

    // stage layer-0a while computing grW = b0 + rownorm(gsum) @ Wg
    stageA128(msgb, row0, tid, sA);
    stageW128(W0a, tid, sB);
    if (tid < HID) {
        float g = gsumIn[tid];
        float s = g * g;
#pragma unroll
        for (int off = 1; off < 64; off <<= 1) s += __shfl_xor(s, off);
        if ((tid & 63) == 0) s_red[tid >> 6] = s;
    }
    __syncthreads();
    if (tid < HID) {
        float inv = 1.f / (sqrtf(s_red[0] + s_red[1]) + 1e-8f);
        s_gr[tid] = gsumIn[tid] * inv;
    }
    __syncthreads();
    if (tid < HID) {
        float a = b0[tid];
#pragma unroll 4
        for (int k = 0; k < HID; k++) a += s_gr[k] * Wg[k * HID + tid];
        s_grW[tid] = a;
    }
    __syncthreads();
    set_bias(acc, s_grW, wcol, ln15);
    mac<4>(sA, sB, wrow, wcol, ln15, quad, acc);     // msg @ W0a
    __syncthreads();
    stageA128(hbin, row0, tid, sA);
    stageW128(W0b, tid, sB);
    __syncthreads();
    mac<4>(sA, sB, wrow, wcol, ln15, quad, acc);     // + h @ W0b
    __syncthreads();
    acc_to_sA(acc, sA, wrow, wcol, ln15, quad);
    stageW128(W1t, tid, sB);
    set_bias(acc, b1, wcol, ln15);
    __syncthreads();
    mac<4>(sA, sB, wrow, wcol, ln15, quad, acc);
    __syncthreads();
    acc_to_sA(acc, sA, wrow, wcol, ln15, quad);
    stageW128(W2t, tid, sB);
    set_bias(acc, b2, wcol, ln15);
    __syncthreads();
    mac<4>(sA, sB, wrow, wcol, ln15, quad, acc);

    // epilogue: row-norm, has_in mask, optional column-sum for next iter
    __syncthreads();                      // sA free -> reduction scratch
    float* s_rs = (float*)sA;             // [64] row sum-of-squares
    float* s_cs = (float*)sA + 64;        // [128] col sums
    if (tid < 64) s_rs[tid] = 0.f;
    else if (tid < 192) s_cs[tid - 64] = 0.f;
    __syncthreads();
#pragma unroll
    for (int mi = 0; mi < 2; mi++)
#pragma unroll
        for (int r = 0; r < 4; r++) {
            float p = 0.f;
#pragma unroll
            for (int ni = 0; ni < 4; ni++) { float v = acc[mi][ni][r]; p += v * v; }
            p += __shfl_xor(p, 1); p += __shfl_xor(p, 2);
            p += __shfl_xor(p, 4); p += __shfl_xor(p, 8);
            if (ln15 == 0) atomicAdd(&s_rs[wrow + mi * 16 + quad * 4 + r], p);
        }
    __syncthreads();
    float csum[4] = {0.f, 0.f, 0.f, 0.f};
#pragma unroll
    for (int mi = 0; mi < 2; mi++)
#pragma unroll
        for (int r = 0; r < 4; r++) {
            int rl = wrow + mi * 16 + quad * 4 + r;
            int row = row0 + rl;
            if (row < n) {
                bool upd = deg[row] > 0;
                float inv = 1.f / (sqrtf(s_rs[rl]) + 1e-8f);
#pragma unroll
                for (int ni = 0; ni < 4; ni++) {
                    int col = wcol + ni * 16 + ln15;
                    float v;
                    if (upd) {
                        v = acc[mi][ni][r] * inv;
                        h[(size_t)row * HID + col] = v;
                        hb[(size_t)row * HID + col] = f2b(v);
                    } else {
                        v = COLSUM ? h[(size_t)row * HID + col] : 0.f;
                    }
                    if (COLSUM) csum[ni] += v;
                }
            }
        }
    if (COLSUM) {
#pragma unroll
        for (int ni = 0; ni < 4; ni++) {
            float p = csum[ni];
            p += __shfl_xor(p, 16);
            p += __shfl_xor(p, 32);
            if (quad == 0) atomicAdd(&s_cs[wcol + ni * 16 + ln15], p);
        }
        __syncthreads();
        if (tid < HID) atomicAdd(&gsumOut[tid], s_cs[tid]);
    }
}

// ---------------- launch ----------------

static inline char* align_up(char* p, size_t a) {
    return (char*)(((uintptr_t)p + a - 1) & ~(uintptr_t)(a - 1));
}

extern "C" void kernel_launch(void* const* d_in, const int* in_sizes, int n_in,
                              void* d_out, int out_size, void* d_ws, size_t ws_size,
                              hipStream_t stream) {
    const float* feat = (const float*)d_in[0];
    const int* src = (const int*)d_in[1];
    const int* dst = (const int*)d_in[2];
    const float* iW0 = (const float*)d_in[3];
    const float* ib0 = (const float*)d_in[4];
    const float* iW1 = (const float*)d_in[5];
    const float* ib1 = (const float*)d_in[6];
    const float* iW2 = (const float*)d_in[7];
    const float* ib2 = (const float*)d_in[8];
    const float* nW0 = (const float*)d_in[9];
    const float* nb0 = (const float*)d_in[10];
    const float* nW1 = (const float*)d_in[11];
    const float* nb1 = (const float*)d_in[12];
    const float* nW2 = (const float*)d_in[13];
    const float* nb2 = (const float*)d_in[14];

    int N = in_sizes[0] / IN_DIM;
    int E = in_sizes[1];
    int n_iter = in_sizes[10] / HID;
    int NB = (N + (1 << NBSH) - 1) >> NBSH;
    float* h = (float*)d_out;

    char* w = (char*)d_ws;
    size_t big2 = (size_t)(N + 64) * HID * sizeof(u16);
    u16* hb   = (u16*)w; w += big2;
    u16* msgb = (u16*)w; w += big2;
    float* gsums = (float*)w; w += (size_t)(n_iter + 1) * HID * sizeof(float);
    u16* Wt = (u16*)w; w += (size_t)(2048 + 2 * 16384 + n_iter * 4 * 16384) * sizeof(u16);
    w = align_up(w, 16);
    int* deg = (int*)w; w += (size_t)N * 4;  w = align_up(w, 16);
    int* row_ptr = (int*)w; w += (size_t)(N + 1) * 4;  w = align_up(w, 16);
    int* cnt = (int*)w; w += (size_t)N * 4;  w = align_up(w, 16);
    int* bcnt = (int*)w; w += (size_t)NB * BPAD * 4;  w = align_up(w, 16);
    int* srcs = (int*)w; w += (size_t)E * 4;  w = align_up(w, 16);
    int2* ebuf = (int2*)w; w += (size_t)E * 8;
    (void)ws_size; (void)n_in; (void)out_size;

    // Wt layout offsets (bf16 elems)
    const int OFF_IW0 = 0;
    const int OFF_IW1 = 2048;
    const int OFF_IW2 = 2048 + 16384;
    const int OFF_IT = 2048 + 2 * 16384;  // per iter: W0a, W0b, W1, W2 (4 x 16384)

    WJobs jobs;
    int nj = 0;
    jobs.src[nj] = iW0; jobs.dstoff[nj] = OFF_IW0; jobs.ks[nj] = 4; nj++;
    jobs.src[nj] = iW1; jobs.dstoff[nj] = OFF_IW1; jobs.ks[nj] = 7; nj++;
    jobs.src[nj] = iW2; jobs.dstoff[nj] = OFF_IW2; jobs.ks[nj] = 7; nj++;
    for (int i = 0; i < n_iter && nj + 4 <= 16; i++) {
        int base = OFF_IT + i * 4 * 16384;
        jobs.src[nj] = nW0 + (size_t)i * 3 * HID * HID;               jobs.dstoff[nj] = base;             jobs.ks[nj] = 7; nj++;
        jobs.src[nj] = nW0 + (size_t)i * 3 * HID * HID + HID * HID;   jobs.dstoff[nj] = base + 16384;     jobs.ks[nj] = 7; nj++;
        jobs.src[nj] = nW1 + (size_t)i * HID * HID;                   jobs.dstoff[nj] = base + 2 * 16384; jobs.ks[nj] = 7; nj++;
        jobs.src[nj] = nW2 + (size_t)i * HID * HID;                   jobs.dstoff[nj] = base + 3 * 16384; jobs.ks[nj] = 7; nj++;
    }

    hipMemsetAsync(deg, 0, (size_t)N * 4, stream);
    hipMemsetAsync(gsums, 0, (size_t)(n_iter + 1) * HID * sizeof(float), stream);

    wprep_k<<<nj, 256, 0, stream>>>(jobs, Wt);

    int eg = (E + 255) / 256;
    count_k<<<eg, 256, 0, stream>>>(dst, deg, E);
    scan_k<<<1, 1024, 0, stream>>>(deg, row_ptr, cnt, bcnt, N, NB);
    bin_k<<<eg, 256, 0, stream>>>(src, dst, bcnt, ebuf, E);
    fill2_k<<<NB, 256, 0, stream>>>(ebuf, row_ptr, cnt, srcs, N);

    int gb = (N + 63) / 64;
    int rb = (N + 3) / 4;
    init_fused_k<<<gb, 256, 0, stream>>>(feat, Wt + OFF_IW0, Wt + OFF_IW1, Wt + OFF_IW2,
                                         ib0, ib1, ib2, h, hb, gsums, N);

    for (int i = 0; i < n_iter; i++) {
        const u16* Wit = Wt + OFF_IT + (size_t)i * 4 * 16384;
        const float* Wg = nW0 + (size_t)i * 3 * HID * HID + 2 * HID * HID;
        msg_k<<<rb, 256, 0, stream>>>(hb, row_ptr, srcs, msgb, N);
        if (i + 1 < n_iter) {
            node_fused_k<true><<<gb, 256, 0, stream>>>(msgb, hb, Wit, Wit + 16384, Wit + 2 * 16384,
                                                       Wit + 3 * 16384, nb0 + (size_t)i * HID, Wg,
                                                       gsums + (size_t)i * HID, nb1 + (size_t)i * HID,
                                                       nb2 + (size_t)i * HID, deg, h, hb,
                                                       gsums + (size_t)(i + 1) * HID, N);
        } else {
            node_fused_k<false><<<gb, 256, 0, stream>>>(msgb, hb, Wit, Wit + 16384, Wit + 2 * 16384,
                                                        Wit + 3 * 16384, nb0 + (size_t)i * HID, Wg,
                                                        gsums + (size_t)i * HID, nb1 + (size_t)i * HID,
                                                        nb2 + (size_t)i * HID, deg, h, hb,
                                                        nullptr, N);
        }
    }
}